// Round 8
// baseline (769.535 us; speedup 1.0000x reference)
//
#include <hip/hip_runtime.h>
#include <hip/hip_fp16.h>
#include <math.h>

#define T_SEQ 1152

typedef _Float16 f16x8 __attribute__((ext_vector_type(8)));
typedef float f32x4 __attribute__((ext_vector_type(4)));

// ---------------------------------------------------------------------------
// Kernel A v8: conv(32x1,8->8,SAME) + LN(8) + ReLU + graph/spatial projection.
// GEMM with swapped operands: A = K (rows f, 16 rows = f@t | f@t+16 via
// kh-shift trick), B = X (cols t). K-dim = 48 kh x 8 i = 384 (12 MFMA of K=32,
// zero-padded). Each MFMA yields 16t x {8f@t, 8f@t+16} -> 25% fewer MFMAs and
// A-reads than the R7 structure, no wasted lanes.
// Block 256 = 4 waves: wave (h = t-half of 64-tile, g = c-half). 8 c-parts of
// 8 channels, per wave 4 c2/part. XS double-buffered (1 barrier/part), global
// loads issued before compute (T14). LN via 1 shfl_xor(16). M computed
// in-kernel to LDS. Final g-merge + coalesced store through reused XS space.
// ---------------------------------------------------------------------------
__global__ __launch_bounds__(256, 4)
void convKernel(const float* __restrict__ X, const float* __restrict__ Kw,
                const float* __restrict__ lnS, const float* __restrict__ lnB,
                const float* __restrict__ L, const float* __restrict__ sw,
                float* __restrict__ snn) {
  __shared__ int4  XS[2][8 * 97];   // [buf][c2][tl] fp16x8 rows; also reused as Red
  __shared__ float Ms[256];         // [c][s]

  const int bid  = blockIdx.x;      // 0..1151
  const int b    = bid / 18;
  const int tile = bid - b * 18;    // 0..17
  const int t0   = tile * 64;
  const int tid  = threadIdx.x;     // 0..255
  const int lane = tid & 63;
  const int wid  = tid >> 6;        // 0..3
  const int h    = wid & 1;         // t-half (0: t0.., 1: t0+32..)
  const int g    = wid >> 1;        // c-half (c2 = g*4 + cc)
  const int w32  = h * 32;
  const int tcol = lane & 15;       // B col = local t
  const int rg   = lane >> 4;       // k-group; C/D rows rg*4+r
  const int fA   = lane & 15;       // A row id for K-frag build

  // ---- A-frags (K), 12 k-slices; rows 0-7: K[kh], rows 8-15: K[kh-16]
  f16x8 ka[12];
  #pragma unroll
  for (int q = 0; q < 12; ++q) {
    const int kh = 4 * q + rg;
    #pragma unroll
    for (int j = 0; j < 8; ++j) {
      float kv = 0.f;
      if (fA < 8) { if (kh < 32) kv = Kw[kh * 64 + j * 8 + fA]; }
      else { int k2 = kh - 16; if (k2 >= 0 && k2 < 32) kv = Kw[k2 * 64 + j * 8 + fA - 8]; }
      ka[q][j] = (_Float16)kv;
    }
  }

  // ---- LN params for this lane's rows: f = (rg&1)*4 + r
  const float4 lnSlo = *(const float4*)lnS,       lnShi = *(const float4*)(lnS + 4);
  const float4 lnBlo = *(const float4*)lnB,       lnBhi = *(const float4*)(lnB + 4);
  const bool hiQ = (rg & 1);
  const float lnSq[4] = { hiQ ? lnShi.x : lnSlo.x, hiQ ? lnShi.y : lnSlo.y,
                          hiQ ? lnShi.z : lnSlo.z, hiQ ? lnShi.w : lnSlo.w };
  const float lnBq[4] = { hiQ ? lnBhi.x : lnBlo.x, hiQ ? lnBhi.y : lnBlo.y,
                          hiQ ? lnBhi.z : lnBlo.z, hiQ ? lnBhi.w : lnBlo.w };

  // ---- staging geometry (unchanged mapping): 760 rows = 8 c2 x 95 tl
  const int sc2 = tid & 7;
  int  stl[3]; long gb[3]; bool tv[3];
  #pragma unroll
  for (int k = 0; k < 3; ++k) {
    stl[k] = (tid >> 3) + 32 * k;
    int tt = t0 - 15 + stl[k];
    tv[k] = (stl[k] < 95) && (tt >= 0) && (tt < T_SEQ);
    gb[k] = (long)tt * 512 + sc2 * 8;
  }
  const float* xb = X + (size_t)(b * T_SEQ) * 512;

  float4 pf0[3], pf1[3];
  // ---- prologue: issue part-0 loads, compute Ms, write XS[0]
  #pragma unroll
  for (int k = 0; k < 3; ++k) {
    pf0[k] = make_float4(0.f,0.f,0.f,0.f); pf1[k] = pf0[k];
    if (tv[k]) { const float* p = xb + gb[k]; pf0[k] = *(const float4*)p; pf1[k] = *(const float4*)(p+4); }
  }
  {
    int m = tid >> 2, s = tid & 3;
    float a = 0.f;
    #pragma unroll 8
    for (int n = 0; n < 64; ++n)
      a = fmaf(sw[n * 4 + s], L[(b * 64 + n) * 64 + m], a);
    Ms[m * 4 + s] = a;
  }
  #pragma unroll
  for (int k = 0; k < 3; ++k) {
    if (stl[k] < 95) {
      unsigned u0 = __builtin_bit_cast(unsigned, __float22half2_rn(make_float2(pf0[k].x, pf0[k].y)));
      unsigned u1 = __builtin_bit_cast(unsigned, __float22half2_rn(make_float2(pf0[k].z, pf0[k].w)));
      unsigned u2 = __builtin_bit_cast(unsigned, __float22half2_rn(make_float2(pf1[k].x, pf1[k].y)));
      unsigned u3 = __builtin_bit_cast(unsigned, __float22half2_rn(make_float2(pf1[k].z, pf1[k].w)));
      int4 v; v.x=(int)u0; v.y=(int)u1; v.z=(int)u2; v.w=(int)u3;
      XS[0][sc2 * 97 + stl[k]] = v;
    }
  }
  __syncthreads();

  float pacc[4][4];
  #pragma unroll
  for (int r = 0; r < 4; ++r)
    #pragma unroll
    for (int s = 0; s < 4; ++s) pacc[r][s] = 0.f;

  #pragma unroll 1
  for (int part = 0; part < 8; ++part) {
    // ---- issue next part's loads (in flight across compute)
    if (part < 7) {
      const float* xp = xb + (part + 1) * 64;
      #pragma unroll
      for (int k = 0; k < 3; ++k) {
        pf0[k] = make_float4(0.f,0.f,0.f,0.f); pf1[k] = pf0[k];
        if (tv[k]) { const float* p = xp + gb[k]; pf0[k] = *(const float4*)p; pf1[k] = *(const float4*)(p+4); }
      }
    }

    // ---- compute: 4 c2 x (12 MFMA + LN + proj)
    const int4* xsb = XS[part & 1];
    #pragma unroll 1
    for (int cc = 0; cc < 4; ++cc) {
      const int c2 = g * 4 + cc;
      f32x4 acc = {0.f, 0.f, 0.f, 0.f};
      const int rb = c2 * 97 + w32 + tcol + rg;
      #pragma unroll
      for (int q = 0; q < 12; ++q) {
        f16x8 xf = __builtin_bit_cast(f16x8, xsb[rb + 4 * q]);
        acc = __builtin_amdgcn_mfma_f32_16x16x32_f16(ka[q], xf, acc, 0, 0, 0);
      }
      // LN over f (8 rows = rg-pair) : one shfl_xor(16)
      float s1 = (acc[0] + acc[1]) + (acc[2] + acc[3]);
      float s2 = fmaf(acc[0], acc[0], fmaf(acc[1], acc[1],
                 fmaf(acc[2], acc[2], acc[3] * acc[3])));
      s1 += __shfl_xor(s1, 16, 64);
      s2 += __shfl_xor(s2, 16, 64);
      float mu = s1 * 0.125f;
      float var = fmaf(-mu, mu, s2 * 0.125f);
      float rs = 1.0f / sqrtf(var + 1e-6f);
      const float4 Mc = *(const float4*)&Ms[(part * 8 + c2) * 4];
      #pragma unroll
      for (int r = 0; r < 4; ++r) {
        float hr = fmaxf(fmaf((acc[r] - mu) * rs, lnSq[r], lnBq[r]), 0.f);
        pacc[r][0] = fmaf(hr, Mc.x, pacc[r][0]);
        pacc[r][1] = fmaf(hr, Mc.y, pacc[r][1]);
        pacc[r][2] = fmaf(hr, Mc.z, pacc[r][2]);
        pacc[r][3] = fmaf(hr, Mc.w, pacc[r][3]);
      }
    }

    // ---- write next buffer, single barrier per part
    if (part < 7) {
      #pragma unroll
      for (int k = 0; k < 3; ++k) {
        if (stl[k] < 95) {
          unsigned u0 = __builtin_bit_cast(unsigned, __float22half2_rn(make_float2(pf0[k].x, pf0[k].y)));
          unsigned u1 = __builtin_bit_cast(unsigned, __float22half2_rn(make_float2(pf0[k].z, pf0[k].w)));
          unsigned u2 = __builtin_bit_cast(unsigned, __float22half2_rn(make_float2(pf1[k].x, pf1[k].y)));
          unsigned u3 = __builtin_bit_cast(unsigned, __float22half2_rn(make_float2(pf1[k].z, pf1[k].w)));
          int4 v; v.x=(int)u0; v.y=(int)u1; v.z=(int)u2; v.w=(int)u3;
          XS[(part + 1) & 1][sc2 * 97 + stl[k]] = v;
        }
      }
    }
    __syncthreads();
  }

  // ---- merge c-halves + coalesced store via Red (aliases XS; reads done)
  float* RedF = (float*)&XS[0][0];     // 4*64*17 floats = 17.4 KB < 24.8 KB
  {
    const int base = (wid * 64 + lane) * 17;
    #pragma unroll
    for (int r = 0; r < 4; ++r)
      #pragma unroll
      for (int s = 0; s < 4; ++s) RedF[base + r * 4 + s] = pacc[r][s];
  }
  __syncthreads();
  {
    // thread -> output (tt = tid>>2, cols (tid&3)*8 .. +7), sum g=0 + g=1
    const int tt = tid >> 2, s = tid & 3;
    const int hh = tt >> 5, tl15 = tt & 15, rgHi = (tt >> 4) & 1;
    float v[8];
    #pragma unroll
    for (int cc = 0; cc < 8; ++cc) {
      const int flo = cc >> 2, r = cc & 3;
      const int ln = (rgHi * 2 + flo) * 16 + tl15;
      v[cc] = RedF[((0 * 2 + hh) * 64 + ln) * 17 + r * 4 + s]
            + RedF[((1 * 2 + hh) * 64 + ln) * 17 + r * 4 + s];
    }
    float* op = snn + ((size_t)b * T_SEQ + t0 + tt) * 32 + s * 8;
    *(float4*)op       = make_float4(v[0], v[1], v[2], v[3]);
    *(float4*)(op + 4) = make_float4(v[4], v[5], v[6], v[7]);
  }
}

// ---------------------------------------------------------------------------
// Kernel B: LIF scan, 16 blocks x 64 threads, 2 chains/thread (ILP),
// ping-pong 24-deep prefetch so loads never stall the dependent chain.
// ---------------------------------------------------------------------------
#define LIF_STEP(M1,M2,MO,S1,S2,ACCS,ACCE,XV,U)                        \
  { M1 = M1 * 0.8f + (XV);                                             \
    float sp1 = (M1 > 0.5f) ? 1.f : 0.f;  M1 -= sp1 * 0.5f;            \
    M2 = M2 * 0.9f + sp1;                                              \
    float sp2 = (M2 > 0.5f) ? 1.f : 0.f;  M2 -= sp2 * 0.5f;            \
    MO = MO * 0.95f + sp2;                                             \
    S1 += sp1; S2 += sp2;                                              \
    if ((U) < 12) ACCS += MO; else ACCE += MO; }

__global__ void scanKernel(const float* __restrict__ snn, float* __restrict__ flat,
                           float* __restrict__ spkPart) {
  const int tid = threadIdx.x;        // 0..63
  const int j = tid & 31;
  const int g = tid >> 5;
  const int pr = blockIdx.x * 2 + g;
  const int b0 = pr * 2, b1 = b0 + 1;
  const float* base0 = snn + (size_t)b0 * T_SEQ * 32 + j;
  const float* base1 = snn + (size_t)b1 * T_SEQ * 32 + j;

  float m10=0.f,m20=0.f,mo0=0.f,s10=0.f,s20=0.f;
  float m11=0.f,m21=0.f,mo1=0.f,s11=0.f,s21=0.f;
  float xA0[24], xA1[24], xB0[24], xB1[24];

  #pragma unroll
  for (int u = 0; u < 24; ++u) { xA0[u] = base0[(size_t)u*32]; xA1[u] = base1[(size_t)u*32]; }

  #pragma unroll 1
  for (int chp = 0; chp < 24; ++chp) {
    const int ch = chp * 2;
    #pragma unroll
    for (int u = 0; u < 24; ++u) {
      int t = (ch + 1) * 24 + u;
      xB0[u] = base0[(size_t)t*32]; xB1[u] = base1[(size_t)t*32];
    }
    {
      float aS0=0.f,aE0=0.f,aS1=0.f,aE1=0.f;
      #pragma unroll
      for (int u = 0; u < 24; ++u) {
        LIF_STEP(m10,m20,mo0,s10,s20,aS0,aE0,xA0[u],u)
        LIF_STEP(m11,m21,mo1,s11,s21,aS1,aE1,xA1[u],u)
      }
      flat[b0*3072 + ch*64 + j]      = aS0 / 12.0f;
      flat[b0*3072 + ch*64 + 32 + j] = aE0 / 12.0f;
      flat[b1*3072 + ch*64 + j]      = aS1 / 12.0f;
      flat[b1*3072 + ch*64 + 32 + j] = aE1 / 12.0f;
    }
    if (chp < 23) {
      #pragma unroll
      for (int u = 0; u < 24; ++u) {
        int t = (ch + 2) * 24 + u;
        xA0[u] = base0[(size_t)t*32]; xA1[u] = base1[(size_t)t*32];
      }
    }
    {
      float aS0=0.f,aE0=0.f,aS1=0.f,aE1=0.f;
      #pragma unroll
      for (int u = 0; u < 24; ++u) {
        LIF_STEP(m10,m20,mo0,s10,s20,aS0,aE0,xB0[u],u)
        LIF_STEP(m11,m21,mo1,s11,s21,aS1,aE1,xB1[u],u)
      }
      flat[b0*3072 + (ch+1)*64 + j]      = aS0 / 12.0f;
      flat[b0*3072 + (ch+1)*64 + 32 + j] = aE0 / 12.0f;
      flat[b1*3072 + (ch+1)*64 + j]      = aS1 / 12.0f;
      flat[b1*3072 + (ch+1)*64 + 32 + j] = aE1 / 12.0f;
    }
  }
  for (int off = 16; off > 0; off >>= 1) {
    s10 += __shfl_down(s10, off, 32);
    s20 += __shfl_down(s20, off, 32);
    s11 += __shfl_down(s11, off, 32);
    s21 += __shfl_down(s21, off, 32);
  }
  if (j == 0) {
    spkPart[b0*2] = s10; spkPart[b0*2+1] = s20;
    spkPart[b1*2] = s11; spkPart[b1*2+1] = s21;
  }
}

// ---------------------------------------------------------------------------
// Kernel C: y = gelu(flat @ W1 + b1); logits = y @ W2 + b2 ; firing rate.
// ---------------------------------------------------------------------------
__global__ void mlpKernel(const float* __restrict__ flat, const float* __restrict__ W1,
                          const float* __restrict__ b1, const float* __restrict__ W2,
                          const float* __restrict__ b2, const float* __restrict__ spkPart,
                          float* __restrict__ out) {
  if (blockIdx.x == 64) {
    if (threadIdx.x == 0) {
      float s1 = 0.f, s2 = 0.f;
      for (int i = 0; i < 64; ++i) { s1 += spkPart[2*i]; s2 += spkPart[2*i+1]; }
      out[256] = (s1 + s2) * 0.5f / (64.0f * 1152.0f * 32.0f);
    }
    return;
  }
  const int b = blockIdx.x;
  const int tid = threadIdx.x;        // 256
  const int u = tid & 31, kc = tid >> 5;
  __shared__ float red[256];
  __shared__ float ys[32];
  float p = 0.f;
  const int kbeg = kc * 384, kend = kbeg + 384;
  #pragma unroll 4
  for (int k = kbeg; k < kend; ++k)
    p = fmaf(flat[b*3072 + k], W1[k*32 + u], p);
  red[tid] = p;
  __syncthreads();
  if (kc == 0) {
    float y = b1[u];
    #pragma unroll
    for (int q = 0; q < 8; ++q) y += red[q*32 + u];
    float y3 = y * y * y;
    float th = tanhf(0.7978845608028654f * (y + 0.044715f * y3));
    ys[u] = 0.5f * y * (1.0f + th);
  }
  __syncthreads();
  if (tid < 4) {
    float accv = b2[tid];
    #pragma unroll
    for (int q = 0; q < 32; ++q) accv = fmaf(ys[q], W2[q*4 + tid], accv);
    out[b*4 + tid] = accv;
  }
}

// ---------------------------------------------------------------------------
extern "C" void kernel_launch(void* const* d_in, const int* in_sizes, int n_in,
                              void* d_out, int out_size, void* d_ws, size_t ws_size,
                              hipStream_t stream) {
  const float* L   = (const float*)d_in[0];
  const float* X   = (const float*)d_in[1];
  // d_in[2] = deterministic (unused)
  const float* Kw  = (const float*)d_in[3];
  const float* lnS = (const float*)d_in[4];
  const float* lnB = (const float*)d_in[5];
  const float* sw  = (const float*)d_in[6];
  const float* W1  = (const float*)d_in[7];
  const float* b1  = (const float*)d_in[8];
  const float* W2  = (const float*)d_in[9];
  const float* b2  = (const float*)d_in[10];

  float* ws   = (float*)d_ws;
  float* snn  = ws;                       // 64*1152*32 = 2359296
  float* flat = snn + 2359296;            // 64*3072    = 196608
  float* spk  = flat + 196608;            // 128
  float* out  = (float*)d_out;

  convKernel<<<1152, 256, 0, stream>>>(X, Kw, lnS, lnB, L, sw, snn);
  scanKernel<<<16, 64, 0, stream>>>(snn, flat, spk);
  mlpKernel<<<65, 256, 0, stream>>>(flat, W1, b1, W2, b2, spk, out);
}

// Round 9
// 196.691 us; speedup vs baseline: 3.9124x; 3.9124x over previous
//
#include <hip/hip_runtime.h>
#include <hip/hip_fp16.h>
#include <math.h>

#define T_SEQ 1152

typedef _Float16 f16x8 __attribute__((ext_vector_type(8)));
typedef float f32x4 __attribute__((ext_vector_type(4)));

// ---------------------------------------------------------------------------
// Kernel A v8: conv(32x1,8->8,SAME) + LN(8) + ReLU + graph/spatial projection.
// GEMM with swapped operands: A = K (rows f, 16 rows = f@t | f@t+16 via
// kh-shift trick), B = X (cols t). K-dim = 48 kh x 8 i = 384 (12 MFMA of K=32,
// zero-padded). Each MFMA yields 16t x {8f@t, 8f@t+16}.
// Block 256 = 4 waves: wave (h = t-half of 64-tile, g = c-half). 8 c-parts of
// 8 channels, per wave 4 c2/part. XS double-buffered (1 barrier/part), global
// loads issued before compute (T14). LN via 1 shfl_xor(16). M computed
// in-kernel to LDS. Final g-merge + coalesced store through reused XS space.
// ---------------------------------------------------------------------------
__global__ __launch_bounds__(256, 4)
void convKernel(const float* __restrict__ X, const float* __restrict__ Kw,
                const float* __restrict__ lnS, const float* __restrict__ lnB,
                const float* __restrict__ L, const float* __restrict__ sw,
                float* __restrict__ snn) {
  __shared__ int4  XS[2][8 * 97];   // [buf][c2][tl] fp16x8 rows; also reused as Red
  __shared__ float Ms[256];         // [c][s]

  const int bid  = blockIdx.x;      // 0..1151
  const int b    = bid / 18;
  const int tile = bid - b * 18;    // 0..17
  const int t0   = tile * 64;
  const int tid  = threadIdx.x;     // 0..255
  const int lane = tid & 63;
  const int wid  = tid >> 6;        // 0..3
  const int h    = wid & 1;         // t-half (0: t0.., 1: t0+32..)
  const int g    = wid >> 1;        // c-half (c2 = g*4 + cc)
  const int w32  = h * 32;
  const int tcol = lane & 15;       // B col = local t
  const int rg   = lane >> 4;       // k-group; C/D rows rg*4+r
  const int fA   = lane & 15;       // A row id for K-frag build

  // ---- A-frags (K), 12 k-slices; rows 0-7: K[kh], rows 8-15: K[kh-16]
  f16x8 ka[12];
  #pragma unroll
  for (int q = 0; q < 12; ++q) {
    const int kh = 4 * q + rg;
    #pragma unroll
    for (int j = 0; j < 8; ++j) {
      float kv = 0.f;
      if (fA < 8) { if (kh < 32) kv = Kw[kh * 64 + j * 8 + fA]; }
      else { int k2 = kh - 16; if (k2 >= 0 && k2 < 32) kv = Kw[k2 * 64 + j * 8 + fA - 8]; }
      ka[q][j] = (_Float16)kv;
    }
  }

  // ---- LN params for this lane's rows: f = (rg&1)*4 + r
  const float4 lnSlo = *(const float4*)lnS,       lnShi = *(const float4*)(lnS + 4);
  const float4 lnBlo = *(const float4*)lnB,       lnBhi = *(const float4*)(lnB + 4);
  const bool hiQ = (rg & 1);
  const float lnSq[4] = { hiQ ? lnShi.x : lnSlo.x, hiQ ? lnShi.y : lnSlo.y,
                          hiQ ? lnShi.z : lnSlo.z, hiQ ? lnShi.w : lnSlo.w };
  const float lnBq[4] = { hiQ ? lnBhi.x : lnBlo.x, hiQ ? lnBhi.y : lnBlo.y,
                          hiQ ? lnBhi.z : lnBlo.z, hiQ ? lnBhi.w : lnBlo.w };

  // ---- staging geometry: 760 rows = 8 c2 x 95 tl
  const int sc2 = tid & 7;
  int  stl[3]; long gb[3]; bool tv[3];
  #pragma unroll
  for (int k = 0; k < 3; ++k) {
    stl[k] = (tid >> 3) + 32 * k;
    int tt = t0 - 15 + stl[k];
    tv[k] = (stl[k] < 95) && (tt >= 0) && (tt < T_SEQ);
    gb[k] = (long)tt * 512 + sc2 * 8;
  }
  const float* xb = X + (size_t)(b * T_SEQ) * 512;

  float4 pf0[3], pf1[3];
  // ---- prologue: issue part-0 loads, compute Ms, write XS[0]
  #pragma unroll
  for (int k = 0; k < 3; ++k) {
    pf0[k] = make_float4(0.f,0.f,0.f,0.f); pf1[k] = pf0[k];
    if (tv[k]) { const float* p = xb + gb[k]; pf0[k] = *(const float4*)p; pf1[k] = *(const float4*)(p+4); }
  }
  {
    int m = tid >> 2, s = tid & 3;
    float a = 0.f;
    #pragma unroll 8
    for (int n = 0; n < 64; ++n)
      a = fmaf(sw[n * 4 + s], L[(b * 64 + n) * 64 + m], a);
    Ms[m * 4 + s] = a;
  }
  #pragma unroll
  for (int k = 0; k < 3; ++k) {
    if (stl[k] < 95) {
      unsigned u0 = __builtin_bit_cast(unsigned, __float22half2_rn(make_float2(pf0[k].x, pf0[k].y)));
      unsigned u1 = __builtin_bit_cast(unsigned, __float22half2_rn(make_float2(pf0[k].z, pf0[k].w)));
      unsigned u2 = __builtin_bit_cast(unsigned, __float22half2_rn(make_float2(pf1[k].x, pf1[k].y)));
      unsigned u3 = __builtin_bit_cast(unsigned, __float22half2_rn(make_float2(pf1[k].z, pf1[k].w)));
      int4 v; v.x=(int)u0; v.y=(int)u1; v.z=(int)u2; v.w=(int)u3;
      XS[0][sc2 * 97 + stl[k]] = v;
    }
  }
  __syncthreads();

  float pacc[4][4];
  #pragma unroll
  for (int r = 0; r < 4; ++r)
    #pragma unroll
    for (int s = 0; s < 4; ++s) pacc[r][s] = 0.f;

  #pragma unroll 1
  for (int part = 0; part < 8; ++part) {
    // ---- issue next part's loads (in flight across compute)
    if (part < 7) {
      const float* xp = xb + (part + 1) * 64;
      #pragma unroll
      for (int k = 0; k < 3; ++k) {
        pf0[k] = make_float4(0.f,0.f,0.f,0.f); pf1[k] = pf0[k];
        if (tv[k]) { const float* p = xp + gb[k]; pf0[k] = *(const float4*)p; pf1[k] = *(const float4*)(p+4); }
      }
    }

    // ---- compute: 4 c2 x (12 MFMA + LN + proj)
    const int4* xsb = XS[part & 1];
    #pragma unroll 1
    for (int cc = 0; cc < 4; ++cc) {
      const int c2 = g * 4 + cc;
      f32x4 acc = {0.f, 0.f, 0.f, 0.f};
      const int rb = c2 * 97 + w32 + tcol + rg;
      #pragma unroll
      for (int q = 0; q < 12; ++q) {
        f16x8 xf = __builtin_bit_cast(f16x8, xsb[rb + 4 * q]);
        acc = __builtin_amdgcn_mfma_f32_16x16x32_f16(ka[q], xf, acc, 0, 0, 0);
      }
      // LN over f (8 rows = rg-pair) : one shfl_xor(16)
      float s1 = (acc[0] + acc[1]) + (acc[2] + acc[3]);
      float s2 = fmaf(acc[0], acc[0], fmaf(acc[1], acc[1],
                 fmaf(acc[2], acc[2], acc[3] * acc[3])));
      s1 += __shfl_xor(s1, 16, 64);
      s2 += __shfl_xor(s2, 16, 64);
      float mu = s1 * 0.125f;
      float var = fmaf(-mu, mu, s2 * 0.125f);
      float rs = 1.0f / sqrtf(var + 1e-6f);
      const float4 Mc = *(const float4*)&Ms[(part * 8 + c2) * 4];
      #pragma unroll
      for (int r = 0; r < 4; ++r) {
        float hr = fmaxf(fmaf((acc[r] - mu) * rs, lnSq[r], lnBq[r]), 0.f);
        pacc[r][0] = fmaf(hr, Mc.x, pacc[r][0]);
        pacc[r][1] = fmaf(hr, Mc.y, pacc[r][1]);
        pacc[r][2] = fmaf(hr, Mc.z, pacc[r][2]);
        pacc[r][3] = fmaf(hr, Mc.w, pacc[r][3]);
      }
    }

    // ---- write next buffer, single barrier per part
    if (part < 7) {
      #pragma unroll
      for (int k = 0; k < 3; ++k) {
        if (stl[k] < 95) {
          unsigned u0 = __builtin_bit_cast(unsigned, __float22half2_rn(make_float2(pf0[k].x, pf0[k].y)));
          unsigned u1 = __builtin_bit_cast(unsigned, __float22half2_rn(make_float2(pf0[k].z, pf0[k].w)));
          unsigned u2 = __builtin_bit_cast(unsigned, __float22half2_rn(make_float2(pf1[k].x, pf1[k].y)));
          unsigned u3 = __builtin_bit_cast(unsigned, __float22half2_rn(make_float2(pf1[k].z, pf1[k].w)));
          int4 v; v.x=(int)u0; v.y=(int)u1; v.z=(int)u2; v.w=(int)u3;
          XS[(part + 1) & 1][sc2 * 97 + stl[k]] = v;
        }
      }
    }
    __syncthreads();
  }

  // ---- merge c-halves + coalesced store via Red (aliases XS; reads done)
  float* RedF = (float*)&XS[0][0];     // 4*64*17 floats = 17.4 KB < 24.8 KB
  {
    const int base = (wid * 64 + lane) * 17;
    #pragma unroll
    for (int r = 0; r < 4; ++r)
      #pragma unroll
      for (int s = 0; s < 4; ++s) RedF[base + r * 4 + s] = pacc[r][s];
  }
  __syncthreads();
  {
    // thread -> output (tt = tid>>2, cols (tid&3)*8 .. +7), sum g=0 + g=1
    const int tt = tid >> 2, s = tid & 3;
    const int hh = tt >> 5, tl15 = tt & 15, rgHi = (tt >> 4) & 1;
    float v[8];
    #pragma unroll
    for (int cc = 0; cc < 8; ++cc) {
      const int flo = cc >> 2, r = cc & 3;
      const int ln = (rgHi * 2 + flo) * 16 + tl15;
      v[cc] = RedF[((0 * 2 + hh) * 64 + ln) * 17 + r * 4 + s]
            + RedF[((1 * 2 + hh) * 64 + ln) * 17 + r * 4 + s];
    }
    float* op = snn + ((size_t)b * T_SEQ + t0 + tt) * 32 + s * 8;
    *(float4*)op       = make_float4(v[0], v[1], v[2], v[3]);
    *(float4*)(op + 4) = make_float4(v[4], v[5], v[6], v[7]);
  }
}

// ---------------------------------------------------------------------------
// Kernel B: LIF scan — R7-benched structure (no spills): 16 blocks x 64
// threads, 2 chains/thread, 12-deep ping-pong prefetch. launch_bounds(64,1)
// gives the allocator the full VGPR budget so buffers stay in registers.
// ---------------------------------------------------------------------------
__global__ __launch_bounds__(64, 1)
void scanKernel(const float* __restrict__ snn, float* __restrict__ flat,
                float* __restrict__ spkPart) {
  const int tid = threadIdx.x;        // 0..63
  const int j = tid & 31;
  const int g = tid >> 5;             // 0..1
  const int pr = blockIdx.x * 2 + g;  // pair 0..31
  const int b0 = pr * 2, b1 = b0 + 1;
  const float* base0 = snn + (size_t)b0 * T_SEQ * 32 + j;
  const float* base1 = snn + (size_t)b1 * T_SEQ * 32 + j;

  float m10 = 0.f, m20 = 0.f, mo0 = 0.f, s10 = 0.f, s20 = 0.f;
  float m11 = 0.f, m21 = 0.f, mo1 = 0.f, s11 = 0.f, s21 = 0.f;

  for (int ch = 0; ch < 48; ++ch) {
    float parts0[2], parts1[2];
    #pragma unroll
    for (int half = 0; half < 2; ++half) {
      float x0[12], x1[12];
      #pragma unroll
      for (int u = 0; u < 12; ++u) {
        int t = ch * 24 + half * 12 + u;
        x0[u] = base0[(size_t)t * 32];
        x1[u] = base1[(size_t)t * 32];
      }
      float acc0 = 0.f, acc1 = 0.f;
      #pragma unroll
      for (int u = 0; u < 12; ++u) {
        m10 = m10 * 0.8f + x0[u];
        float sp1a = (m10 > 0.5f) ? 1.f : 0.f;  m10 -= sp1a * 0.5f;
        m20 = m20 * 0.9f + sp1a;
        float sp2a = (m20 > 0.5f) ? 1.f : 0.f;  m20 -= sp2a * 0.5f;
        mo0 = mo0 * 0.95f + sp2a;
        s10 += sp1a; s20 += sp2a; acc0 += mo0;

        m11 = m11 * 0.8f + x1[u];
        float sp1b = (m11 > 0.5f) ? 1.f : 0.f;  m11 -= sp1b * 0.5f;
        m21 = m21 * 0.9f + sp1b;
        float sp2b = (m21 > 0.5f) ? 1.f : 0.f;  m21 -= sp2b * 0.5f;
        mo1 = mo1 * 0.95f + sp2b;
        s11 += sp1b; s21 += sp2b; acc1 += mo1;
      }
      parts0[half] = acc0; parts1[half] = acc1;
    }
    flat[b0 * 3072 + ch * 64 + j]      = parts0[0] / 12.0f;
    flat[b0 * 3072 + ch * 64 + 32 + j] = parts0[1] / 12.0f;
    flat[b1 * 3072 + ch * 64 + j]      = parts1[0] / 12.0f;
    flat[b1 * 3072 + ch * 64 + 32 + j] = parts1[1] / 12.0f;
  }
  for (int off = 16; off > 0; off >>= 1) {
    s10 += __shfl_down(s10, off, 32);
    s20 += __shfl_down(s20, off, 32);
    s11 += __shfl_down(s11, off, 32);
    s21 += __shfl_down(s21, off, 32);
  }
  if (j == 0) {
    spkPart[b0 * 2] = s10; spkPart[b0 * 2 + 1] = s20;
    spkPart[b1 * 2] = s11; spkPart[b1 * 2 + 1] = s21;
  }
}

// ---------------------------------------------------------------------------
// Kernel C: y = gelu(flat @ W1 + b1); logits = y @ W2 + b2 ; firing rate.
// ---------------------------------------------------------------------------
__global__ void mlpKernel(const float* __restrict__ flat, const float* __restrict__ W1,
                          const float* __restrict__ b1, const float* __restrict__ W2,
                          const float* __restrict__ b2, const float* __restrict__ spkPart,
                          float* __restrict__ out) {
  if (blockIdx.x == 64) {
    if (threadIdx.x == 0) {
      float s1 = 0.f, s2 = 0.f;
      for (int i = 0; i < 64; ++i) { s1 += spkPart[2*i]; s2 += spkPart[2*i+1]; }
      out[256] = (s1 + s2) * 0.5f / (64.0f * 1152.0f * 32.0f);
    }
    return;
  }
  const int b = blockIdx.x;
  const int tid = threadIdx.x;        // 256
  const int u = tid & 31, kc = tid >> 5;
  __shared__ float red[256];
  __shared__ float ys[32];
  float p = 0.f;
  const int kbeg = kc * 384, kend = kbeg + 384;
  #pragma unroll 4
  for (int k = kbeg; k < kend; ++k)
    p = fmaf(flat[b*3072 + k], W1[k*32 + u], p);
  red[tid] = p;
  __syncthreads();
  if (kc == 0) {
    float y = b1[u];
    #pragma unroll
    for (int q = 0; q < 8; ++q) y += red[q*32 + u];
    float y3 = y * y * y;
    float th = tanhf(0.7978845608028654f * (y + 0.044715f * y3));
    ys[u] = 0.5f * y * (1.0f + th);
  }
  __syncthreads();
  if (tid < 4) {
    float accv = b2[tid];
    #pragma unroll
    for (int q = 0; q < 32; ++q) accv = fmaf(ys[q], W2[q*4 + tid], accv);
    out[b*4 + tid] = accv;
  }
}

// ---------------------------------------------------------------------------
extern "C" void kernel_launch(void* const* d_in, const int* in_sizes, int n_in,
                              void* d_out, int out_size, void* d_ws, size_t ws_size,
                              hipStream_t stream) {
  const float* L   = (const float*)d_in[0];
  const float* X   = (const float*)d_in[1];
  // d_in[2] = deterministic (unused)
  const float* Kw  = (const float*)d_in[3];
  const float* lnS = (const float*)d_in[4];
  const float* lnB = (const float*)d_in[5];
  const float* sw  = (const float*)d_in[6];
  const float* W1  = (const float*)d_in[7];
  const float* b1  = (const float*)d_in[8];
  const float* W2  = (const float*)d_in[9];
  const float* b2  = (const float*)d_in[10];

  float* ws   = (float*)d_ws;
  float* snn  = ws;                       // 64*1152*32 = 2359296
  float* flat = snn + 2359296;            // 64*3072    = 196608
  float* spk  = flat + 196608;            // 128
  float* out  = (float*)d_out;

  convKernel<<<1152, 256, 0, stream>>>(X, Kw, lnS, lnB, L, sw, snn);
  scanKernel<<<16, 64, 0, stream>>>(snn, flat, spk);
  mlpKernel<<<65, 256, 0, stream>>>(flat, W1, b1, W2, b2, spk, out);
}

// Round 10
// 178.716 us; speedup vs baseline: 4.3059x; 1.1006x over previous
//
#include <hip/hip_runtime.h>
#include <hip/hip_fp16.h>
#include <math.h>

#define T_SEQ 1152

typedef _Float16 f16x8 __attribute__((ext_vector_type(8)));
typedef float f32x4 __attribute__((ext_vector_type(4)));

// ---------------------------------------------------------------------------
// Kernel 0: M[b,m,s] = sum_n spatial_w[n,s] * L_norm[b,n,m]  ([b][m][s] layout)
// ---------------------------------------------------------------------------
__global__ void mKernel(const float* __restrict__ L, const float* __restrict__ sw,
                        float* __restrict__ Mbuf) {
  int b = blockIdx.x, tid = threadIdx.x;   // 256 threads
  int s = tid >> 6, m = tid & 63;
  float a = 0.f;
  #pragma unroll 4
  for (int n = 0; n < 64; ++n)
    a = fmaf(sw[n * 4 + s], L[(b * 64 + n) * 64 + m], a);
  Mbuf[b * 256 + m * 4 + s] = a;
}

// ---------------------------------------------------------------------------
// Kernel A v10: conv + LN + ReLU + projection, BARRIER-FREE main loop.
// Same GEMM as v8 (A=K dual-shift 16 rows, B=X cols=t, K-dim 384 = 12 MFMA).
// Each wave (h = t-half, g = c-half) stages ITS OWN 63 rows x 4 channels into
// a private LDS region (4.3 KB); write->read ordering is wave-local lgkmcnt,
// so the 8-part loop has ZERO __syncthreads. 16 waves/CU run unsynchronized.
// Prefetch next part's 8 float4 into regs before compute (T14).
// 2 barriers total (final g-merge through reused LDS).
// ---------------------------------------------------------------------------
__global__ __launch_bounds__(256, 4)
void convKernel(const float* __restrict__ X, const float* __restrict__ Kw,
                const float* __restrict__ lnS, const float* __restrict__ lnB,
                const float* __restrict__ Mbuf, float* __restrict__ snn) {
  __shared__ int4 XS[4 * 4 * 68];   // [wid][c2][row(63,pad68)] = 17408 B; Red alias

  const int bid  = blockIdx.x;      // 0..1151
  const int b    = bid / 18;
  const int tile = bid - b * 18;    // 0..17
  const int t0   = tile * 64;
  const int tid  = threadIdx.x;     // 0..255
  const int lane = tid & 63;
  const int wid  = tid >> 6;        // 0..3
  const int h    = wid & 1;         // t-half
  const int g    = wid >> 1;        // c-half
  const int w32  = h * 32;
  const int tcol = lane & 15;       // B col = local t
  const int rg   = lane >> 4;       // k-group; C/D rows rg*4+r
  const int fA   = lane & 15;       // A row id for K-frag build

  // ---- A-frags (K), 12 k-slices; rows 0-7: K[kh], rows 8-15: K[kh-16]
  f16x8 ka[12];
  #pragma unroll
  for (int q = 0; q < 12; ++q) {
    const int kh = 4 * q + rg;
    #pragma unroll
    for (int j = 0; j < 8; ++j) {
      float kv = 0.f;
      if (fA < 8) { if (kh < 32) kv = Kw[kh * 64 + j * 8 + fA]; }
      else { int k2 = kh - 16; if (k2 >= 0 && k2 < 32) kv = Kw[k2 * 64 + j * 8 + fA - 8]; }
      ka[q][j] = (_Float16)kv;
    }
  }

  // ---- LN params for this lane's rows: f = (rg&1)*4 + r
  const float4 lnSlo = *(const float4*)lnS,       lnShi = *(const float4*)(lnS + 4);
  const float4 lnBlo = *(const float4*)lnB,       lnBhi = *(const float4*)(lnB + 4);
  const bool hiQ = (rg & 1);
  const float lnSq[4] = { hiQ ? lnShi.x : lnSlo.x, hiQ ? lnShi.y : lnSlo.y,
                          hiQ ? lnShi.z : lnSlo.z, hiQ ? lnShi.w : lnSlo.w };
  const float lnBq[4] = { hiQ ? lnBhi.x : lnBlo.x, hiQ ? lnBhi.y : lnBlo.y,
                          hiQ ? lnBhi.z : lnBlo.z, hiQ ? lnBhi.w : lnBlo.w };

  // ---- staging: lane = row (0..62), 4 channels per wave per part
  const int srow = lane;
  const int stT  = t0 + w32 - 15 + srow;            // global t of this row
  const bool sv  = (srow < 63) && (stT >= 0) && (stT < T_SEQ);
  const bool srv = (srow < 63);
  const float* xb = X + (size_t)(b * T_SEQ) * 512;
  int4* wXS = XS + wid * 272;

  // ---- prologue: stage part 0 (direct)
  #pragma unroll
  for (int c2 = 0; c2 < 4; ++c2) {
    if (srv) {
      float4 a0 = make_float4(0.f,0.f,0.f,0.f), a1 = a0;
      if (sv) {
        const float* p = xb + (size_t)stT * 512 + (g * 4 + c2) * 8;
        a0 = *(const float4*)p; a1 = *(const float4*)(p + 4);
      }
      unsigned u0 = __builtin_bit_cast(unsigned, __float22half2_rn(make_float2(a0.x, a0.y)));
      unsigned u1 = __builtin_bit_cast(unsigned, __float22half2_rn(make_float2(a0.z, a0.w)));
      unsigned u2 = __builtin_bit_cast(unsigned, __float22half2_rn(make_float2(a1.x, a1.y)));
      unsigned u3 = __builtin_bit_cast(unsigned, __float22half2_rn(make_float2(a1.z, a1.w)));
      int4 v; v.x=(int)u0; v.y=(int)u1; v.z=(int)u2; v.w=(int)u3;
      wXS[c2 * 68 + srow] = v;
    }
  }

  float pacc[4][4];
  #pragma unroll
  for (int r = 0; r < 4; ++r)
    #pragma unroll
    for (int s = 0; s < 4; ++s) pacc[r][s] = 0.f;

  #pragma unroll 1
  for (int part = 0; part < 8; ++part) {
    // ---- prefetch next part's rows into regs (in flight across compute)
    float4 pf0[4], pf1[4];
    if (part < 7) {
      const int chb = (part + 1) * 8 + g * 4;
      #pragma unroll
      for (int c2 = 0; c2 < 4; ++c2) {
        pf0[c2] = make_float4(0.f,0.f,0.f,0.f); pf1[c2] = pf0[c2];
        if (sv) {
          const float* p = xb + (size_t)stT * 512 + (chb + c2) * 8;
          pf0[c2] = *(const float4*)p; pf1[c2] = *(const float4*)(p + 4);
        }
      }
    }

    // ---- compute: 4 c2 x (12 MFMA + LN + proj), no barriers
    #pragma unroll 2
    for (int cc = 0; cc < 4; ++cc) {
      f32x4 acc = {0.f, 0.f, 0.f, 0.f};
      const int4* rb = wXS + cc * 68 + tcol + rg;
      #pragma unroll
      for (int q = 0; q < 12; ++q) {
        f16x8 xf = __builtin_bit_cast(f16x8, rb[4 * q]);
        acc = __builtin_amdgcn_mfma_f32_16x16x32_f16(ka[q], xf, acc, 0, 0, 0);
      }
      // LN over f (8 rows = rg-pair): one shfl_xor(16)
      float s1 = (acc[0] + acc[1]) + (acc[2] + acc[3]);
      float s2 = fmaf(acc[0], acc[0], fmaf(acc[1], acc[1],
                 fmaf(acc[2], acc[2], acc[3] * acc[3])));
      s1 += __shfl_xor(s1, 16, 64);
      s2 += __shfl_xor(s2, 16, 64);
      float mu = s1 * 0.125f;
      float var = fmaf(-mu, mu, s2 * 0.125f);
      float rs = 1.0f / sqrtf(var + 1e-6f);
      const float4 Mc = *(const float4*)(Mbuf + b * 256 + (part * 8 + g * 4 + cc) * 4);
      #pragma unroll
      for (int r = 0; r < 4; ++r) {
        float hr = fmaxf(fmaf((acc[r] - mu) * rs, lnSq[r], lnBq[r]), 0.f);
        pacc[r][0] = fmaf(hr, Mc.x, pacc[r][0]);
        pacc[r][1] = fmaf(hr, Mc.y, pacc[r][1]);
        pacc[r][2] = fmaf(hr, Mc.z, pacc[r][2]);
        pacc[r][3] = fmaf(hr, Mc.w, pacc[r][3]);
      }
    }

    // ---- write prefetched rows (wave-local; lgkmcnt orders vs reads above)
    if (part < 7) {
      #pragma unroll
      for (int c2 = 0; c2 < 4; ++c2) {
        if (srv) {
          unsigned u0 = __builtin_bit_cast(unsigned, __float22half2_rn(make_float2(pf0[c2].x, pf0[c2].y)));
          unsigned u1 = __builtin_bit_cast(unsigned, __float22half2_rn(make_float2(pf0[c2].z, pf0[c2].w)));
          unsigned u2 = __builtin_bit_cast(unsigned, __float22half2_rn(make_float2(pf1[c2].x, pf1[c2].y)));
          unsigned u3 = __builtin_bit_cast(unsigned, __float22half2_rn(make_float2(pf1[c2].z, pf1[c2].w)));
          int4 v; v.x=(int)u0; v.y=(int)u1; v.z=(int)u2; v.w=(int)u3;
          wXS[c2 * 68 + srow] = v;
        }
      }
    }
  }

  // ---- merge c-halves + coalesced store via Red (aliases XS)
  __syncthreads();                     // all waves done reading XS
  float* RedF = (float*)&XS[0];        // 4352 floats = 4*64*17
  {
    const int base = (wid * 64 + lane) * 17;
    #pragma unroll
    for (int r = 0; r < 4; ++r)
      #pragma unroll
      for (int s = 0; s < 4; ++s) RedF[base + r * 4 + s] = pacc[r][s];
  }
  __syncthreads();
  {
    // thread -> output (tt = tid>>2, cols (tid&3)*8 .. +7), sum g=0 + g=1
    const int tt = tid >> 2, s = tid & 3;
    const int hh = tt >> 5, tl15 = tt & 15, rgHi = (tt >> 4) & 1;
    float v[8];
    #pragma unroll
    for (int cc = 0; cc < 8; ++cc) {
      const int flo = cc >> 2, r = cc & 3;
      const int ln = (rgHi * 2 + flo) * 16 + tl15;
      v[cc] = RedF[((0 * 2 + hh) * 64 + ln) * 17 + r * 4 + s]
            + RedF[((1 * 2 + hh) * 64 + ln) * 17 + r * 4 + s];
    }
    float* op = snn + ((size_t)b * T_SEQ + t0 + tt) * 32 + s * 8;
    *(float4*)op       = make_float4(v[0], v[1], v[2], v[3]);
    *(float4*)(op + 4) = make_float4(v[4], v[5], v[6], v[7]);
  }
}

// ---------------------------------------------------------------------------
// Kernel B: LIF scan — 1 chain/thread (32 blocks x 64 thr = 2048 chains),
// 24-deep ping-pong prefetch; dependent-chain floor ~8 us.
// ---------------------------------------------------------------------------
__global__ __launch_bounds__(64, 1)
void scanKernel(const float* __restrict__ snn, float* __restrict__ flat,
                float* __restrict__ spkPart) {
  const int tid = threadIdx.x;        // 0..63
  const int j = tid & 31;
  const int b = blockIdx.x * 2 + (tid >> 5);
  const float* base = snn + (size_t)b * T_SEQ * 32 + j;

  float m1 = 0.f, m2 = 0.f, mo = 0.f, s1 = 0.f, s2 = 0.f;
  float cur[24], nxt[24];
  #pragma unroll
  for (int u = 0; u < 24; ++u) cur[u] = base[(size_t)u * 32];

  #pragma unroll 1
  for (int ch = 0; ch < 48; ++ch) {
    if (ch < 47) {
      #pragma unroll
      for (int u = 0; u < 24; ++u) nxt[u] = base[(size_t)((ch + 1) * 24 + u) * 32];
    }
    float aS = 0.f, aE = 0.f;
    #pragma unroll
    for (int u = 0; u < 24; ++u) {
      m1 = m1 * 0.8f + cur[u];
      float sp1 = (m1 > 0.5f) ? 1.f : 0.f;  m1 -= sp1 * 0.5f;
      m2 = m2 * 0.9f + sp1;
      float sp2 = (m2 > 0.5f) ? 1.f : 0.f;  m2 -= sp2 * 0.5f;
      mo = mo * 0.95f + sp2;
      s1 += sp1; s2 += sp2;
      if (u < 12) aS += mo; else aE += mo;
    }
    flat[b * 3072 + ch * 64 + j]      = aS / 12.0f;
    flat[b * 3072 + ch * 64 + 32 + j] = aE / 12.0f;
    if (ch < 47) {
      #pragma unroll
      for (int u = 0; u < 24; ++u) cur[u] = nxt[u];
    }
  }
  for (int off = 16; off > 0; off >>= 1) {
    s1 += __shfl_down(s1, off, 32);
    s2 += __shfl_down(s2, off, 32);
  }
  if (j == 0) { spkPart[b * 2] = s1; spkPart[b * 2 + 1] = s2; }
}

// ---------------------------------------------------------------------------
// Kernel C: y = gelu(flat @ W1 + b1); logits = y @ W2 + b2 ; firing rate.
// ---------------------------------------------------------------------------
__global__ void mlpKernel(const float* __restrict__ flat, const float* __restrict__ W1,
                          const float* __restrict__ b1, const float* __restrict__ W2,
                          const float* __restrict__ b2, const float* __restrict__ spkPart,
                          float* __restrict__ out) {
  if (blockIdx.x == 64) {
    if (threadIdx.x == 0) {
      float s1 = 0.f, s2 = 0.f;
      for (int i = 0; i < 64; ++i) { s1 += spkPart[2*i]; s2 += spkPart[2*i+1]; }
      out[256] = (s1 + s2) * 0.5f / (64.0f * 1152.0f * 32.0f);
    }
    return;
  }
  const int b = blockIdx.x;
  const int tid = threadIdx.x;        // 256
  const int u = tid & 31, kc = tid >> 5;
  __shared__ float red[256];
  __shared__ float ys[32];
  float p = 0.f;
  const int kbeg = kc * 384, kend = kbeg + 384;
  #pragma unroll 4
  for (int k = kbeg; k < kend; ++k)
    p = fmaf(flat[b*3072 + k], W1[k*32 + u], p);
  red[tid] = p;
  __syncthreads();
  if (kc == 0) {
    float y = b1[u];
    #pragma unroll
    for (int q = 0; q < 8; ++q) y += red[q*32 + u];
    float y3 = y * y * y;
    float th = tanhf(0.7978845608028654f * (y + 0.044715f * y3));
    ys[u] = 0.5f * y * (1.0f + th);
  }
  __syncthreads();
  if (tid < 4) {
    float accv = b2[tid];
    #pragma unroll
    for (int q = 0; q < 32; ++q) accv = fmaf(ys[q], W2[q*4 + tid], accv);
    out[b*4 + tid] = accv;
  }
}

// ---------------------------------------------------------------------------
extern "C" void kernel_launch(void* const* d_in, const int* in_sizes, int n_in,
                              void* d_out, int out_size, void* d_ws, size_t ws_size,
                              hipStream_t stream) {
  const float* L   = (const float*)d_in[0];
  const float* X   = (const float*)d_in[1];
  // d_in[2] = deterministic (unused)
  const float* Kw  = (const float*)d_in[3];
  const float* lnS = (const float*)d_in[4];
  const float* lnB = (const float*)d_in[5];
  const float* sw  = (const float*)d_in[6];
  const float* W1  = (const float*)d_in[7];
  const float* b1  = (const float*)d_in[8];
  const float* W2  = (const float*)d_in[9];
  const float* b2  = (const float*)d_in[10];

  float* ws   = (float*)d_ws;
  float* Mbuf = ws;                       // 64*4*64    = 16384
  float* snn  = Mbuf + 16384;             // 64*1152*32 = 2359296
  float* flat = snn + 2359296;            // 64*3072    = 196608
  float* spk  = flat + 196608;            // 128
  float* out  = (float*)d_out;

  mKernel<<<64, 256, 0, stream>>>(L, sw, Mbuf);
  convKernel<<<1152, 256, 0, stream>>>(X, Kw, lnS, lnB, Mbuf, snn);
  scanKernel<<<32, 64, 0, stream>>>(snn, flat, spk);
  mlpKernel<<<65, 256, 0, stream>>>(flat, W1, b1, W2, b2, spk, out);
}